// Round 12
// baseline (448.358 us; speedup 1.0000x reference)
//
#include <hip/hip_runtime.h>
#include <stdint.h>

#define DIMD 512
#define ROWS 65536

#define GRID  1024
#define BLOCK 256
#define WPB   4                 // waves per block
#define RPW   16                // rows per wave (64 rows/block)
#define LDSR  3                 // rows per wave parked in LDS (12/block)

#define NFLAG       64          // replicated barrier-exit flags
#define FLAG_STRIDE 32          // ints -> 128 B between flag copies

typedef float vfloat4 __attribute__((ext_vector_type(4)));

__device__ __forceinline__ float dist8(const float4 wa, const float4 wb,
                                       const float4 xa, const float4 xb)
{
    float s = 0.0f, t;
    t = wa.x - xa.x; s = fmaf(t, t, s);
    t = wa.y - xa.y; s = fmaf(t, t, s);
    t = wa.z - xa.z; s = fmaf(t, t, s);
    t = wa.w - xa.w; s = fmaf(t, t, s);
    t = wb.x - xb.x; s = fmaf(t, t, s);
    t = wb.y - xb.y; s = fmaf(t, t, s);
    t = wb.z - xb.z; s = fmaf(t, t, s);
    t = wb.w - xb.w; s = fmaf(t, t, s);
    return s;
}

__device__ __forceinline__ void update_row(const float4 wa, const float4 wb,
                                           const float4 xa, const float4 xb,
                                           int row, unsigned bmu,
                                           float bi, float bj,
                                           float alpha_op, float inv_s2,
                                           float* __restrict__ winner,
                                           float* __restrict__ new_weights,
                                           int lane)
{
    const float di = (float)(row >> 8) - bi;
    const float dj = (float)(row & 255) - bj;
    const float coef = alpha_op * __expf(-(di * di + dj * dj) * inv_s2);

    vfloat4 oa, ob;
    oa.x = fmaf(coef, xa.x - wa.x, wa.x);
    oa.y = fmaf(coef, xa.y - wa.y, wa.y);
    oa.z = fmaf(coef, xa.z - wa.z, wa.z);
    oa.w = fmaf(coef, xa.w - wa.w, wa.w);
    ob.x = fmaf(coef, xb.x - wb.x, wb.x);
    ob.y = fmaf(coef, xb.y - wb.y, wb.y);
    ob.z = fmaf(coef, xb.z - wb.z, wb.z);
    ob.w = fmaf(coef, xb.w - wb.w, wb.w);

    vfloat4* o4 = reinterpret_cast<vfloat4*>(new_weights + (size_t)row * DIMD);
    __builtin_nontemporal_store(oa, o4 + lane);
    __builtin_nontemporal_store(ob, o4 + lane + 64);

    if (row == (int)bmu) {
        float4* wn = reinterpret_cast<float4*>(winner);
        wn[lane]      = wa;   // OLD weights row
        wn[lane + 64] = wb;
    }
}

// ===========================================================================
// Single-dispatch fused SOM, non-cooperative spin barrier.
// Co-residency by construction (PROVEN in R11: this exact geometry completed):
// launch_bounds(256,8) -> 64-VGPR cap (actual 60), LDS 24.6KB -> 6 blocks/CU
// capacity; grid 1024 needs 4/CU average. R11's 262us was the SPIN STORM:
// 1024 spinners x s_sleep(2) on ONE line ~= 4G atomic loads/s -> L2 bank
// serialization backs up the fabric and throttles all streaming. Fix:
// 64 replicated exit flags (128B apart, <=16 spinners each) + s_sleep(16)
// (~0.6us poll) -> ~25M loads/s/line, zero fabric pressure.
// ===========================================================================
__global__ __launch_bounds__(BLOCK, 8) void som_fused(
    const float* __restrict__ x,
    const float* __restrict__ w,
    const int* __restrict__ it_ptr,
    unsigned long long* __restrict__ slots,   // [GRID], no init needed
    int* __restrict__ done,                   // [1], memset 0 per call
    int* __restrict__ flags,                  // [NFLAG*FLAG_STRIDE], memset 0
    float* __restrict__ out)
{
    __shared__ float lds[WPB * LDSR * DIMD];      // 24576 B
    __shared__ unsigned long long sred[WPB];      // +32 B

    const int lane = threadIdx.x & 63;
    const int wave = threadIdx.x >> 6;
    const int row0 = (blockIdx.x * WPB + wave) * RPW;

    const float4* x4 = reinterpret_cast<const float4*>(x);
    const float4 xa = x4[lane];
    const float4 xb = x4[lane + 64];
    const float4* w4 = reinterpret_cast<const float4*>(w);

    unsigned long long best = ~0ull;
    float d[8];

    // ---- phase 1, batch A: rows 0..7 (0..2 parked in LDS) ----
    #pragma unroll
    for (int r = 0; r < 8; ++r) {
        const float4* p = w4 + (size_t)(row0 + r) * (DIMD / 4);
        const float4 wa  = p[lane];
        const float4 wbv = p[lane + 64];
        if (r < LDSR) {
            float4* dst = reinterpret_cast<float4*>(
                lds + (wave * LDSR + r) * DIMD);
            dst[lane]      = wa;
            dst[lane + 64] = wbv;
        }
        d[r] = dist8(wa, wbv, xa, xb);
    }
    #pragma unroll
    for (int off = 32; off > 0; off >>= 1) {
        #pragma unroll
        for (int r = 0; r < 8; ++r) d[r] += __shfl_xor(d[r], off, 64);
    }
    #pragma unroll
    for (int r = 0; r < 8; ++r) {
        const unsigned long long key =
            (((unsigned long long)__float_as_uint(d[r])) << 32) |
            (unsigned long long)(unsigned)(row0 + r);
        best = (key < best) ? key : best;
    }

    // ---- phase 1, batch B: rows 8..15 ----
    #pragma unroll
    for (int r = 0; r < 8; ++r) {
        const float4* p = w4 + (size_t)(row0 + 8 + r) * (DIMD / 4);
        d[r] = dist8(p[lane], p[lane + 64], xa, xb);
    }
    #pragma unroll
    for (int off = 32; off > 0; off >>= 1) {
        #pragma unroll
        for (int r = 0; r < 8; ++r) d[r] += __shfl_xor(d[r], off, 64);
    }
    #pragma unroll
    for (int r = 0; r < 8; ++r) {
        const unsigned long long key =
            (((unsigned long long)__float_as_uint(d[r])) << 32) |
            (unsigned long long)(unsigned)(row0 + 8 + r);
        best = (key < best) ? key : best;
    }

    // ---- block-best -> slots[blockIdx]; arrive; low-contention spin ----
    if (lane == 0) sred[wave] = best;
    __syncthreads();
    if (threadIdx.x == 0) {
        unsigned long long b = sred[0];
        #pragma unroll
        for (int i = 1; i < WPB; ++i) b = (sred[i] < b) ? sred[i] : b;
        __hip_atomic_store(&slots[blockIdx.x], b, __ATOMIC_RELEASE,
                           __HIP_MEMORY_SCOPE_AGENT);
        const int old = __hip_atomic_fetch_add(done, 1, __ATOMIC_ACQ_REL,
                                               __HIP_MEMORY_SCOPE_AGENT);
        if (old == GRID - 1) {
            // finisher: publish 64 replicated exit flags
            #pragma unroll
            for (int f = 0; f < NFLAG; ++f)
                __hip_atomic_store(&flags[f * FLAG_STRIDE], 1,
                                   __ATOMIC_RELEASE, __HIP_MEMORY_SCOPE_AGENT);
        } else {
            int* myflag = &flags[(blockIdx.x & (NFLAG - 1)) * FLAG_STRIDE];
            while (__hip_atomic_load(myflag, __ATOMIC_ACQUIRE,
                                     __HIP_MEMORY_SCOPE_AGENT) == 0) {
                __builtin_amdgcn_s_sleep(16);
            }
        }
        __threadfence();
    }
    __syncthreads();

    // ---- global argmin: all threads stride the 1024 slots ----
    unsigned long long g = ~0ull;
    #pragma unroll
    for (int k = 0; k < GRID / BLOCK; ++k) {
        const unsigned long long v = slots[k * BLOCK + threadIdx.x];
        g = (v < g) ? v : g;
    }
    #pragma unroll
    for (int off = 32; off > 0; off >>= 1) {
        const unsigned long long o = __shfl_xor(g, off, 64);
        g = (o < g) ? o : g;
    }
    if (lane == 0) sred[wave] = g;
    __syncthreads();
    g = sred[0];
    #pragma unroll
    for (int i = 1; i < WPB; ++i) g = (sred[i] < g) ? sred[i] : g;

    const unsigned bmu = (unsigned)(g & 0xFFFFFFFFull);
    const float bi = (float)(bmu >> 8);
    const float bj = (float)(bmu & 255u);

    // scalar decay math in double, matching Python semantics
    const double itd      = (double)(*it_ptr);
    const double lr       = 1.0 - itd / 1000.0;
    const float  alpha_op = (float)(0.3 * lr);
    const double sigma_op = 128.0 * lr;           // SIGMA = max(M,N)/2
    const float  inv_s2   = (float)(1.0 / (sigma_op * sigma_op));

    float* winner      = out;          // first 512 floats
    float* new_weights = out + DIMD;   // then 65536 x 512

    // ---- phase 2: global re-read rows first (start HBM streams ASAP) ----
    #pragma unroll 2
    for (int r = LDSR; r < RPW; ++r) {
        const float4* p = w4 + (size_t)(row0 + r) * (DIMD / 4);
        update_row(p[lane], p[lane + 64], xa, xb, row0 + r, bmu,
                   bi, bj, alpha_op, inv_s2, winner, new_weights, lane);
    }

    // ---- phase 2: LDS-parked rows ----
    #pragma unroll
    for (int r = 0; r < LDSR; ++r) {
        const float4* src = reinterpret_cast<const float4*>(
            lds + (wave * LDSR + r) * DIMD);
        update_row(src[lane], src[lane + 64], xa, xb, row0 + r, bmu,
                   bi, bj, alpha_op, inv_s2, winner, new_weights, lane);
    }
}

extern "C" void kernel_launch(void* const* d_in, const int* in_sizes, int n_in,
                              void* d_out, int out_size, void* d_ws, size_t ws_size,
                              hipStream_t stream) {
    const float* x       = (const float*)d_in[0];
    const float* weights = (const float*)d_in[1];
    // d_in[2] = y (unused by the math)
    const int*   it_ptr  = (const int*)d_in[3];

    float* out = (float*)d_out;

    // ws layout: [0,4) done | [128, 128+NFLAG*128) flags | [16384, +8*GRID) slots
    int*                done  = (int*)d_ws;
    int*                flags = (int*)((char*)d_ws + 128);
    unsigned long long* slots = (unsigned long long*)((char*)d_ws + 16384);

    // one memset clears done + all flag replicas (slots need no init)
    hipMemsetAsync(d_ws, 0, 128 + NFLAG * FLAG_STRIDE * sizeof(int), stream);

    som_fused<<<GRID, BLOCK, 0, stream>>>(x, weights, it_ptr, slots, done,
                                          flags, out);
}

// Round 13
// 70.658 us; speedup vs baseline: 6.3455x; 6.3455x over previous
//
#include <hip/hip_runtime.h>
#include <stdint.h>

#define DIMD 512
#define ROWS 65536

#define K_BLOCKS 2048
#define WPB      4              // waves per block
#define RPW      8              // rows per wave: 2048*4*8 = 65536

typedef float vfloat4 __attribute__((ext_vector_type(4)));

// ---------------------------------------------------------------------------
// Kernel 1: BMU search. One wave per 8-row strip, fully unrolled: 8
// independent distance accumulations, then 8 ILP-overlapped butterfly
// reductions. Lane reads float4 chunks (lane) and (lane+64) -> each load
// instruction covers a dense contiguous 1024 B. Key = (dist_bits<<32)|row:
// min-key == min distance with first-index tie-break (distances >= 0, float
// bits order-preserving). Per-block best plain-stored (no init, no atomics).
//
// NOTE (session history): fusing K1+K2 via an in-kernel grid barrier was
// tried exhaustively (R4-R12): cooperative launch is rejected during graph
// capture; hand-rolled agent-scope spin barriers cost 200-500us on this
// 8-XCD part regardless of contention shaping. The kernel boundary IS the
// cheap device-wide barrier (~4us). 402 MB / ~6.3 TB/s ~= 64us floor.
// ---------------------------------------------------------------------------
__global__ __launch_bounds__(256) void som_argmin_kernel(
    const float* __restrict__ x,
    const float* __restrict__ w,
    unsigned long long* __restrict__ slots)
{
    const int lane  = threadIdx.x & 63;
    const int wave  = threadIdx.x >> 6;
    const int gwave = blockIdx.x * WPB + wave;
    const int row0  = gwave * RPW;

    const float4* x4 = reinterpret_cast<const float4*>(x);
    const float4 xa = x4[lane];
    const float4 xb = x4[lane + 64];

    float d[RPW];

    #pragma unroll
    for (int r = 0; r < RPW; ++r) {
        const float4* w4 =
            reinterpret_cast<const float4*>(w + (size_t)(row0 + r) * DIMD);
        const float4 wa = w4[lane];
        const float4 wb = w4[lane + 64];

        float s = 0.0f, t;
        t = wa.x - xa.x; s = fmaf(t, t, s);
        t = wa.y - xa.y; s = fmaf(t, t, s);
        t = wa.z - xa.z; s = fmaf(t, t, s);
        t = wa.w - xa.w; s = fmaf(t, t, s);
        t = wb.x - xb.x; s = fmaf(t, t, s);
        t = wb.y - xb.y; s = fmaf(t, t, s);
        t = wb.z - xb.z; s = fmaf(t, t, s);
        t = wb.w - xb.w; s = fmaf(t, t, s);
        d[r] = s;
    }

    // 8 independent butterfly reductions (ILP-pipelined on the DS pipe).
    #pragma unroll
    for (int off = 32; off > 0; off >>= 1) {
        #pragma unroll
        for (int r = 0; r < RPW; ++r)
            d[r] += __shfl_xor(d[r], off, 64);
    }

    unsigned long long best = ~0ull;
    #pragma unroll
    for (int r = 0; r < RPW; ++r) {
        unsigned long long key =
            (((unsigned long long)__float_as_uint(d[r])) << 32) |
            (unsigned long long)(unsigned)(row0 + r);
        best = (key < best) ? key : best;
    }

    __shared__ unsigned long long sbest[WPB];
    if (lane == 0) sbest[wave] = best;
    __syncthreads();
    if (threadIdx.x == 0) {
        unsigned long long b = sbest[0];
        #pragma unroll
        for (int i = 1; i < WPB; ++i) b = (sbest[i] < b) ? sbest[i] : b;
        slots[blockIdx.x] = b;
    }
}

// ---------------------------------------------------------------------------
// Kernel 2: slot-reduce (2048 x 8 B, L2-hot) -> bmu broadcast -> streaming
// fused update with nontemporal stores (don't evict weights from Infinity
// Cache; output is never re-read). Rows processed in reverse block order
// (K1 streamed rows ascending -> highest rows freshest in IC; neutral-to-
// slightly-positive, measured). Winner = OLD weights[bmu].
// ---------------------------------------------------------------------------
__global__ __launch_bounds__(256) void som_update_kernel(
    const float* __restrict__ x,
    const float* __restrict__ w,
    const int* __restrict__ it_ptr,
    const unsigned long long* __restrict__ slots,
    float* __restrict__ out)
{
    const int lane = threadIdx.x & 63;
    const int wave = threadIdx.x >> 6;

    // ---- reduce the 2048 per-block candidates, broadcast bmu ----
    unsigned long long b = ~0ull;
    for (int i = threadIdx.x; i < K_BLOCKS; i += 256) {
        unsigned long long v = slots[i];
        b = (v < b) ? v : b;
    }
    #pragma unroll
    for (int off = 32; off > 0; off >>= 1) {
        unsigned long long o = __shfl_xor(b, off, 64);
        b = (o < b) ? o : b;
    }
    __shared__ unsigned long long sbest[WPB];
    if (lane == 0) sbest[wave] = b;
    __syncthreads();
    unsigned long long g = sbest[0];
    #pragma unroll
    for (int i = 1; i < WPB; ++i) g = (sbest[i] < g) ? sbest[i] : g;

    const unsigned bmu = (unsigned)(g & 0xFFFFFFFFull);
    const float bi = (float)(bmu >> 8);
    const float bj = (float)(bmu & 255u);

    // scalar decay math in double, matching Python semantics
    const double itd      = (double)(*it_ptr);
    const double lr       = 1.0 - itd / 1000.0;
    const float  alpha_op = (float)(0.3 * lr);
    const double sigma_op = 128.0 * lr;           // SIGMA = max(M,N)/2
    const float  inv_s2   = (float)(1.0 / (sigma_op * sigma_op));

    const float4* x4 = reinterpret_cast<const float4*>(x);
    const float4 xa = x4[lane];
    const float4 xb = x4[lane + 64];

    float* winner      = out;          // first 512 floats
    float* new_weights = out + DIMD;   // then 65536 x 512

    // reversed block order (IC-freshness)
    const int rblk  = (K_BLOCKS - 1) - blockIdx.x;
    const int gwave = rblk * WPB + wave;
    const int row0  = gwave * RPW;

    #pragma unroll
    for (int r = 0; r < RPW; ++r) {
        const int row = row0 + r;
        const float di = (float)(row >> 8) - bi;
        const float dj = (float)(row & 255) - bj;
        const float coef = alpha_op * __expf(-(di * di + dj * dj) * inv_s2);

        const float4* w4 =
            reinterpret_cast<const float4*>(w + (size_t)row * DIMD);
        const float4 wa = w4[lane];
        const float4 wb = w4[lane + 64];

        vfloat4 oa, ob;
        oa.x = fmaf(coef, xa.x - wa.x, wa.x);
        oa.y = fmaf(coef, xa.y - wa.y, wa.y);
        oa.z = fmaf(coef, xa.z - wa.z, wa.z);
        oa.w = fmaf(coef, xa.w - wa.w, wa.w);
        ob.x = fmaf(coef, xb.x - wb.x, wb.x);
        ob.y = fmaf(coef, xb.y - wb.y, wb.y);
        ob.z = fmaf(coef, xb.z - wb.z, wb.z);
        ob.w = fmaf(coef, xb.w - wb.w, wb.w);

        vfloat4* o4 = reinterpret_cast<vfloat4*>(new_weights + (size_t)row * DIMD);
        __builtin_nontemporal_store(oa, o4 + lane);
        __builtin_nontemporal_store(ob, o4 + lane + 64);

        if (row == (int)bmu) {
            float4* wn = reinterpret_cast<float4*>(winner);
            wn[lane]      = wa;   // OLD weights row
            wn[lane + 64] = wb;
        }
    }
}

extern "C" void kernel_launch(void* const* d_in, const int* in_sizes, int n_in,
                              void* d_out, int out_size, void* d_ws, size_t ws_size,
                              hipStream_t stream) {
    const float* x       = (const float*)d_in[0];
    const float* weights = (const float*)d_in[1];
    // d_in[2] = y (unused by the math)
    const int*   it_ptr  = (const int*)d_in[3];

    float* out = (float*)d_out;
    unsigned long long* slots = (unsigned long long*)d_ws;  // 2048 * 8 B

    som_argmin_kernel<<<K_BLOCKS, 256, 0, stream>>>(x, weights, slots);
    som_update_kernel<<<K_BLOCKS, 256, 0, stream>>>(x, weights, it_ptr, slots, out);
}